// Round 1
// baseline (1280.061 us; speedup 1.0000x reference)
//
#include <hip/hip_runtime.h>

// VariationalMPS: <M|H|M> / <M|M> via split-half environment sweeps.
// R3: single persistent kernel. All 42 former dispatches (init, prep,
// 20x(k_A,k_B), dot, loss) fused into one launch; phase ordering enforced by a
// slot/go grid barrier (agent-scope atomics). Grid = 192 blocks <= 256 CUs so
// all blocks are trivially co-resident; phase bodies are verbatim from R2.

#define D 128
#define W 8
#define NS 40
#define HALF 20
#define MSZ (D * 2 * D)      // 32768
#define HSZ (W * W * 2 * 2)  // 256
#define LSZ (D * W * D)      // 131072
#define NSZ (D * D)          // 16384
#define T2SZ (D * W * D * 2) // 262144
#define TNSZ (D * 2 * D)     // 32768

#define OFF_LL 0
#define OFF_LR (OFF_LL + LSZ)
#define OFF_NL (OFF_LR + LSZ)
#define OFF_NR (OFF_NL + NSZ)
#define OFF_T2L (OFF_NR + NSZ)  // 294912 — envs live below this
#define OFF_T2R (OFF_T2L + T2SZ)
#define OFF_TNL (OFF_T2R + T2SZ)
#define OFF_TNR (OFF_TNL + TNSZ)
#define OFF_MREV (OFF_TNR + TNSZ)
#define OFF_HREV (OFF_MREV + HALF * MSZ)
#define OFF_PART (OFF_HREV + HALF * HSZ)   // 128 energy partials
#define OFF_PARTN (OFF_PART + 128)         // 128 norm partials
#define WS_FLOATS (OFF_PARTN + 128)

#define NBLK 192                 // grid: <= 256 CUs -> co-resident by construction
#define OFF_BAR WS_FLOATS        // barrier state (ints), zeroed by k_bzero
#define BAR_INTS (32 * (NBLK + 2))  // go word at [0], slot b at [32*(b+1)]

__global__ __launch_bounds__(256) void k_bzero(float* ws) {
    int idx = blockIdx.x * 256 + threadIdx.x;
    int* bar = (int*)(ws + OFF_BAR);
    if (idx < BAR_INTS) bar[idx] = 0;
}

// Grid barrier: each block release-stores its epoch to its own slot (no
// same-address atomic contention); block 0's threads gather all slots, then
// thread 0 release-stores the go word; everyone else acquire-polls go.
// Release/acquire at agent scope handles cross-XCD L2 writeback/invalidate.
__device__ __forceinline__ void gbar(int* bar, int epoch) {
    __syncthreads();
    if (blockIdx.x == 0) {
        int t = threadIdx.x;
        if (t >= 1 && t < NBLK) {
            while (__hip_atomic_load(&bar[32 * (t + 1)], __ATOMIC_ACQUIRE,
                                     __HIP_MEMORY_SCOPE_AGENT) < epoch)
                __builtin_amdgcn_s_sleep(1);
        }
        __syncthreads();
        if (t == 0)
            __hip_atomic_store(&bar[0], epoch, __ATOMIC_RELEASE,
                               __HIP_MEMORY_SCOPE_AGENT);
    } else {
        if (threadIdx.x == 0) {
            __hip_atomic_store(&bar[32 * (blockIdx.x + 1)], epoch,
                               __ATOMIC_RELEASE, __HIP_MEMORY_SCOPE_AGENT);
            while (__hip_atomic_load(&bar[0], __ATOMIC_ACQUIRE,
                                     __HIP_MEMORY_SCOPE_AGENT) < epoch)
                __builtin_amdgcn_s_sleep(1);
        }
        __syncthreads();
    }
}

__global__ __launch_bounds__(256) void k_sweep(const float* __restrict__ Min,
                                               const float* __restrict__ Hin,
                                               float* __restrict__ ws,
                                               float* __restrict__ out) {
    __shared__ float sm[7680];
    int* bar = (int*)(ws + OFF_BAR);
    const int bid = blockIdx.x;
    const int t = threadIdx.x;
    int ep = 0;

    // ---- phase -1a: env init (was k_init) ----
    for (int idx = bid * 256 + t; idx < OFF_T2L; idx += NBLK * 256) {
        float v = 0.f;
        if (idx == 0) v = 1.f;                         // L_left[0,0,0]
        else if (idx == OFF_LR + (W - 1) * D) v = 1.f; // L_right[0,W-1,0]
        else if (idx == OFF_NL) v = 1.f;               // N_left[0,0]
        else if (idx == OFF_NR) v = 1.f;               // N_right[0,0]
        ws[idx] = v;
    }
    // ---- phase -1b: Mrev/Hrev prep (was k_prep) ----
    for (int idx = bid * 256 + t; idx < HALF * MSZ + HALF * HSZ; idx += NBLK * 256) {
        if (idx < HALF * MSZ) {
            int kk = idx >> 15;
            int r = idx & (MSZ - 1);
            int p = r >> 8;
            int i = (r >> 7) & 1;
            int a = r & 127;
            ws[OFF_MREV + idx] = Min[(NS - 1 - kk) * MSZ + a * 256 + i * 128 + p];
        } else {
            int idx2 = idx - HALF * MSZ;
            int kk = idx2 >> 8;
            int r = idx2 & 255;
            int x = r >> 5, w = (r >> 2) & 7, i = (r >> 1) & 1, j = r & 1;
            ws[OFF_HREV + idx2] = Hin[(NS - 1 - kk) * HSZ + w * 32 + x * 4 + i * 2 + j];
        }
    }
    gbar(bar, ++ep);

    for (int k = 0; k < HALF; ++k) {
        // ================= phase A (was k_A, 192 tasks) =================
        if (bid < 128) {
            int side = bid >> 6;
            int eb = bid & 63;
            int b0 = (eb & 7) * 16;
            int p0 = (eb >> 3) * 16;
            const float* Lsrc = ws + (side ? OFF_LR : OFF_LL);
            const float* m = side ? (ws + OFF_MREV + k * MSZ) : (Min + k * MSZ);
            const float* h = side ? (ws + OFF_HREV + k * HSZ) : (Hin + k * HSZ);
            float* T2 = ws + (side ? OFF_T2R : OFF_T2L);
            float* Ls = sm;          // [32a][16b][8w pad->12], row stride 200
            float* ms = sm + 6400;   // [32a][2i][16p]
            float* hs = sm + 7424;   // [16wi][16xj]
            hs[t] = h[((t >> 4) >> 1) * 32 + ((t & 15) >> 1) * 4 + ((t >> 4) & 1) * 2 + (t & 1)];
            int b_l = t & 15, p_l = t >> 4;
            float acc[8][2];
#pragma unroll
            for (int w = 0; w < 8; ++w) { acc[w][0] = 0.f; acc[w][1] = 0.f; }
            for (int c = 0; c < 4; ++c) {
                int a0 = c * 32;
                __syncthreads();
#pragma unroll
                for (int u = 0; u < 4; ++u) {
                    int e = u * 256 + t;
                    int aa = e >> 5, w = (e >> 2) & 7, bq = e & 3;
                    const float4 v = *(const float4*)&Lsrc[(a0 + aa) * 1024 + w * 128 + b0 + bq * 4];
                    float* dst = &Ls[aa * 200 + bq * 48 + w];
                    dst[0] = v.x; dst[12] = v.y; dst[24] = v.z; dst[36] = v.w;
                }
                {
                    int aa = t >> 3, i = (t >> 2) & 1, pq = t & 3;
                    const float4 v = *(const float4*)&m[(a0 + aa) * 256 + i * 128 + p0 + pq * 4];
                    *(float4*)&ms[aa * 32 + i * 16 + pq * 4] = v;
                }
                __syncthreads();
#pragma unroll 4
                for (int aa = 0; aa < 32; ++aa) {
                    float4 l0 = *(float4*)&Ls[aa * 200 + b_l * 12];
                    float4 l1 = *(float4*)&Ls[aa * 200 + b_l * 12 + 4];
                    float m0 = ms[aa * 32 + p_l];
                    float m1 = ms[aa * 32 + 16 + p_l];
                    acc[0][0] += l0.x * m0; acc[0][1] += l0.x * m1;
                    acc[1][0] += l0.y * m0; acc[1][1] += l0.y * m1;
                    acc[2][0] += l0.z * m0; acc[2][1] += l0.z * m1;
                    acc[3][0] += l0.w * m0; acc[3][1] += l0.w * m1;
                    acc[4][0] += l1.x * m0; acc[4][1] += l1.x * m1;
                    acc[5][0] += l1.y * m0; acc[5][1] += l1.y * m1;
                    acc[6][0] += l1.z * m0; acc[6][1] += l1.z * m1;
                    acc[7][0] += l1.w * m0; acc[7][1] += l1.w * m1;
                }
            }
            float o[16];
#pragma unroll
            for (int xj = 0; xj < 16; ++xj) o[xj] = 0.f;
#pragma unroll
            for (int wi = 0; wi < 16; ++wi) {
                float tv = acc[wi >> 1][wi & 1];
                float4 h0 = *(float4*)&hs[wi * 16];
                float4 h1 = *(float4*)&hs[wi * 16 + 4];
                float4 h2 = *(float4*)&hs[wi * 16 + 8];
                float4 h3 = *(float4*)&hs[wi * 16 + 12];
                o[0] += tv * h0.x;  o[1] += tv * h0.y;  o[2] += tv * h0.z;  o[3] += tv * h0.w;
                o[4] += tv * h1.x;  o[5] += tv * h1.y;  o[6] += tv * h1.z;  o[7] += tv * h1.w;
                o[8] += tv * h2.x;  o[9] += tv * h2.y;  o[10] += tv * h2.z; o[11] += tv * h2.w;
                o[12] += tv * h3.x; o[13] += tv * h3.y; o[14] += tv * h3.z; o[15] += tv * h3.w;
            }
            int b = b0 + b_l, p = p0 + p_l;
            int base = p * 2048 + b * 2; // T2[p][x][b][j]
#pragma unroll
            for (int x = 0; x < 8; ++x) {
                float2 v; v.x = o[x * 2]; v.y = o[x * 2 + 1];
                *(float2*)&T2[base + x * 256] = v;
            }
        } else if (bid < 192) {
            int nb = bid - 128;
            int side = nb >> 5;
            int nn = nb & 31;
            int b0 = (nn & 3) * 32;
            int c0 = (nn >> 2) * 32;
            const float* Nsrc = ws + (side ? OFF_NR : OFF_NL);
            const float* m = side ? (ws + OFF_MREV + k * MSZ) : (Min + k * MSZ);
            float* Tn = ws + (side ? OFF_TNR : OFF_TNL);
            float* As = sm;         // [32][33]
            float* Bs = sm + 1056;  // [32][33]
            int ty = t >> 4, tx = t & 15;
            float a00 = 0, a01 = 0, a10 = 0, a11 = 0;
            for (int c = 0; c < 4; ++c) {
                int a0 = c * 32;
                __syncthreads();
                for (int u = 0; u < 4; ++u) {
                    int e = u * 256 + t;
                    int kk = e >> 5, col = e & 31;
                    As[kk * 33 + col] = Nsrc[(a0 + kk) * 128 + b0 + col];
                    Bs[kk * 33 + col] = m[(a0 + kk) * 256 + c0 + col];
                }
                __syncthreads();
                for (int kk = 0; kk < 32; ++kk) {
                    float av0 = As[kk * 33 + 2 * ty], av1 = As[kk * 33 + 2 * ty + 1];
                    float bv0 = Bs[kk * 33 + 2 * tx], bv1 = Bs[kk * 33 + 2 * tx + 1];
                    a00 += av0 * bv0;
                    a01 += av0 * bv1;
                    a10 += av1 * bv0;
                    a11 += av1 * bv1;
                }
            }
            int b_ = b0 + 2 * ty;
            int ip0 = c0 + 2 * tx, ip1 = ip0 + 1;
            int p0_ = ip0 & 127, i0 = ip0 >> 7;
            int p1_ = ip1 & 127, i1 = ip1 >> 7;
            Tn[p0_ * 256 + b_ * 2 + i0] = a00;
            Tn[p1_ * 256 + b_ * 2 + i1] = a01;
            Tn[p0_ * 256 + (b_ + 1) * 2 + i0] = a10;
            Tn[p1_ * 256 + (b_ + 1) * 2 + i1] = a11;
        }
        gbar(bar, ++ep);

        // ================= phase B (was k_B, 144 tasks) =================
        if (bid < 144) {
            float* As = sm;              // [32][34]
            float* Bs = sm + 32 * 34;    // [32][68]
            const float* A;
            const float* B;
            float* C;
            int r0, c0;
            if (bid < 128) {
                int side = bid >> 6;
                int eb = bid & 63;
                r0 = (eb & 31) * 32;
                c0 = (eb >> 5) * 64;
                A = ws + (side ? OFF_T2R : OFF_T2L);
                B = side ? (ws + OFF_MREV + k * MSZ) : (Min + k * MSZ);
                C = ws + (side ? OFF_LR : OFF_LL);
            } else {
                int nb = bid - 128;
                int side = nb >> 3;
                int nn = nb & 7;
                r0 = (nn & 3) * 32;
                c0 = (nn >> 2) * 64;
                A = ws + (side ? OFF_TNR : OFF_TNL);
                B = side ? (ws + OFF_MREV + k * MSZ) : (Min + k * MSZ);
                C = ws + (side ? OFF_NR : OFF_NL);
            }
            int ty = t >> 4, tx = t & 15;
            float a00 = 0, a01 = 0, a02 = 0, a03 = 0;
            float a10 = 0, a11 = 0, a12 = 0, a13 = 0;
            for (int c = 0; c < 8; ++c) {
                int k0 = c * 32;
                __syncthreads();
                {
                    int rr = t >> 3, kq = t & 7;
                    const float4 v = *(const float4*)&A[(r0 + rr) * 256 + k0 + kq * 4];
                    float* dst = &As[kq * 136 + rr];
                    dst[0] = v.x; dst[34] = v.y; dst[68] = v.z; dst[102] = v.w;
                }
#pragma unroll
                for (int u = 0; u < 2; ++u) {
                    int e = u * 256 + t;
                    int kk = e >> 4, cq = e & 15;
                    const float4 v = *(const float4*)&B[(k0 + kk) * 128 + c0 + cq * 4];
                    *(float4*)&Bs[kk * 68 + cq * 4] = v;
                }
                __syncthreads();
#pragma unroll 8
                for (int kk = 0; kk < 32; ++kk) {
                    float2 av = *(float2*)&As[kk * 34 + 2 * ty];
                    float4 bv = *(float4*)&Bs[kk * 68 + 4 * tx];
                    a00 += av.x * bv.x; a01 += av.x * bv.y; a02 += av.x * bv.z; a03 += av.x * bv.w;
                    a10 += av.y * bv.x; a11 += av.y * bv.y; a12 += av.y * bv.z; a13 += av.y * bv.w;
                }
            }
            int r = r0 + 2 * ty, cc = c0 + 4 * tx;
            float4 v0; v0.x = a00; v0.y = a01; v0.z = a02; v0.w = a03;
            float4 v1; v1.x = a10; v1.y = a11; v1.z = a12; v1.w = a13;
            *(float4*)&C[r * 128 + cc] = v0;
            *(float4*)&C[(r + 1) * 128 + cc] = v1;
        }
        gbar(bar, ++ep);
    }

    // ================= dot partials (was k_dot, 128 tasks) =================
    if (bid < 128) {
        float* se = sm;
        float* sn = sm + 256;
        const float* LL = ws + OFF_LL;
        const float* LR = ws + OFF_LR;
        float e = 0.f;
#pragma unroll
        for (int u = 0; u < 4; ++u) {
            int i = bid * 1024 + u * 256 + t;
            e += LL[i] * LR[i];
        }
        float n = 0.f;
        if (t < 128) {
            int i = bid * 128 + t;
            n = ws[OFF_NL + i] * ws[OFF_NR + i];
        }
        se[t] = e;
        sn[t] = n;
        __syncthreads();
        for (int s = 128; s > 0; s >>= 1) {
            if (t < s) { se[t] += se[t + s]; sn[t] += sn[t + s]; }
            __syncthreads();
        }
        if (t == 0) {
            ws[OFF_PART + bid] = se[0];
            ws[OFF_PARTN + bid] = sn[0];
        }
    }
    gbar(bar, ++ep);

    // ================= final reduce + loss (was k_loss) =================
    if (bid == 0) {
        float* se = sm;
        float* sn = sm + 128;
        if (t < 128) {
            se[t] = ws[OFF_PART + t];
            sn[t] = ws[OFF_PARTN + t];
        }
        __syncthreads();
        for (int s = 64; s > 0; s >>= 1) {
            if (t < s) { se[t] += se[t + s]; sn[t] += sn[t + s]; }
            __syncthreads();
        }
        if (t == 0) {
            float E = se[0], Nm = sn[0];
            out[0] = E;
            out[1] = Nm;
            out[2] = E / Nm;
            out[3] = fmaxf(Nm - 10000.0f, 0.0f);
        }
    }
}

extern "C" void kernel_launch(void* const* d_in, const int* in_sizes, int n_in,
                              void* d_out, int out_size, void* d_ws, size_t ws_size,
                              hipStream_t stream) {
    const float* Min = (const float*)d_in[0];
    const float* Hin = (const float*)d_in[1];
    float* ws = (float*)d_ws;
    float* out = (float*)d_out;
    (void)in_sizes; (void)n_in; (void)out_size; (void)ws_size;

    k_bzero<<<dim3((BAR_INTS + 255) / 256), dim3(256), 0, stream>>>(ws);
    k_sweep<<<dim3(NBLK), dim3(256), 0, stream>>>(Min, Hin, ws, out);
}

// Round 2
// 925.961 us; speedup vs baseline: 1.3824x; 1.3824x over previous
//
#include <hip/hip_runtime.h>

// VariationalMPS: <M|H|M> / <M|M> via split-half environment sweeps.
// R4: persistent kernel (as R3) with a FIXED grid barrier. R3's barrier polled
// with ACQUIRE agent-scope atomic loads -> buffer_inv (full-L2 invalidate) per
// poll iteration -> L2 permanently cold (FETCH_SIZE 73 MB, 124 GB/s, 25 us per
// barrier). R4 spins with RELAXED loads and issues exactly ONE release fence
// (buffer_wbl2) before the slot store and ONE acquire fence (buffer_inv) after
// barrier exit, per block per barrier. Phase bodies verbatim from R2/R3.

#define D 128
#define W 8
#define NS 40
#define HALF 20
#define MSZ (D * 2 * D)      // 32768
#define HSZ (W * W * 2 * 2)  // 256
#define LSZ (D * W * D)      // 131072
#define NSZ (D * D)          // 16384
#define T2SZ (D * W * D * 2) // 262144
#define TNSZ (D * 2 * D)     // 32768

#define OFF_LL 0
#define OFF_LR (OFF_LL + LSZ)
#define OFF_NL (OFF_LR + LSZ)
#define OFF_NR (OFF_NL + NSZ)
#define OFF_T2L (OFF_NR + NSZ)  // 294912 — envs live below this
#define OFF_T2R (OFF_T2L + T2SZ)
#define OFF_TNL (OFF_T2R + T2SZ)
#define OFF_TNR (OFF_TNL + TNSZ)
#define OFF_MREV (OFF_TNR + TNSZ)
#define OFF_HREV (OFF_MREV + HALF * MSZ)
#define OFF_PART (OFF_HREV + HALF * HSZ)   // 128 energy partials
#define OFF_PARTN (OFF_PART + 128)         // 128 norm partials
#define WS_FLOATS (OFF_PARTN + 128)

#define NBLK 192                 // grid: <= 256 CUs -> co-resident by construction
#define OFF_BAR WS_FLOATS        // barrier state (ints), zeroed by k_bzero
#define BAR_INTS (32 * (NBLK + 2))  // go word at [0], slot b at [32*(b+1)]

__global__ __launch_bounds__(256) void k_bzero(float* ws) {
    int idx = blockIdx.x * 256 + threadIdx.x;
    int* bar = (int*)(ws + OFF_BAR);
    if (idx < BAR_INTS) bar[idx] = 0;
}

// Grid barrier. Cache-maintenance discipline: exactly one buffer_wbl2 (release
// fence) and one buffer_inv (acquire fence) per block per barrier; ALL spin
// loads are RELAXED (they go to the coherence point via sc1 without touching
// L2 state). __syncthreads() drains vmcnt(0) first, so all waves' phase
// stores are in L2 before thread 0's release fence writes L2 back to the LLC.
__device__ __forceinline__ void gbar(int* bar, int epoch) {
    __syncthreads();
    if (threadIdx.x == 0) {
        __builtin_amdgcn_fence(__ATOMIC_RELEASE, "agent");   // waitcnt + buffer_wbl2
        __hip_atomic_store(&bar[32 * (blockIdx.x + 1)], epoch,
                           __ATOMIC_RELAXED, __HIP_MEMORY_SCOPE_AGENT);
    }
    if (blockIdx.x == 0) {
        int t = threadIdx.x;
        if (t >= 1 && t < NBLK) {
            while (__hip_atomic_load(&bar[32 * (t + 1)], __ATOMIC_RELAXED,
                                     __HIP_MEMORY_SCOPE_AGENT) < epoch)
                __builtin_amdgcn_s_sleep(4);
        }
        __syncthreads();
        if (t == 0)
            __hip_atomic_store(&bar[0], epoch, __ATOMIC_RELAXED,
                               __HIP_MEMORY_SCOPE_AGENT);
    } else {
        if (threadIdx.x == 0) {
            while (__hip_atomic_load(&bar[0], __ATOMIC_RELAXED,
                                     __HIP_MEMORY_SCOPE_AGENT) < epoch)
                __builtin_amdgcn_s_sleep(4);
        }
        __syncthreads();
    }
    __builtin_amdgcn_fence(__ATOMIC_ACQUIRE, "agent");       // one buffer_inv
}

__global__ __launch_bounds__(256) void k_sweep(const float* __restrict__ Min,
                                               const float* __restrict__ Hin,
                                               float* __restrict__ ws,
                                               float* __restrict__ out) {
    __shared__ float sm[7680];
    int* bar = (int*)(ws + OFF_BAR);
    const int bid = blockIdx.x;
    const int t = threadIdx.x;
    int ep = 0;

    // ---- phase -1a: env init (was k_init) ----
    for (int idx = bid * 256 + t; idx < OFF_T2L; idx += NBLK * 256) {
        float v = 0.f;
        if (idx == 0) v = 1.f;                         // L_left[0,0,0]
        else if (idx == OFF_LR + (W - 1) * D) v = 1.f; // L_right[0,W-1,0]
        else if (idx == OFF_NL) v = 1.f;               // N_left[0,0]
        else if (idx == OFF_NR) v = 1.f;               // N_right[0,0]
        ws[idx] = v;
    }
    // ---- phase -1b: Mrev/Hrev prep (was k_prep) ----
    for (int idx = bid * 256 + t; idx < HALF * MSZ + HALF * HSZ; idx += NBLK * 256) {
        if (idx < HALF * MSZ) {
            int kk = idx >> 15;
            int r = idx & (MSZ - 1);
            int p = r >> 8;
            int i = (r >> 7) & 1;
            int a = r & 127;
            ws[OFF_MREV + idx] = Min[(NS - 1 - kk) * MSZ + a * 256 + i * 128 + p];
        } else {
            int idx2 = idx - HALF * MSZ;
            int kk = idx2 >> 8;
            int r = idx2 & 255;
            int x = r >> 5, w = (r >> 2) & 7, i = (r >> 1) & 1, j = r & 1;
            ws[OFF_HREV + idx2] = Hin[(NS - 1 - kk) * HSZ + w * 32 + x * 4 + i * 2 + j];
        }
    }
    gbar(bar, ++ep);

    for (int k = 0; k < HALF; ++k) {
        // ================= phase A (was k_A, 192 tasks) =================
        if (bid < 128) {
            int side = bid >> 6;
            int eb = bid & 63;
            int b0 = (eb & 7) * 16;
            int p0 = (eb >> 3) * 16;
            const float* Lsrc = ws + (side ? OFF_LR : OFF_LL);
            const float* m = side ? (ws + OFF_MREV + k * MSZ) : (Min + k * MSZ);
            const float* h = side ? (ws + OFF_HREV + k * HSZ) : (Hin + k * HSZ);
            float* T2 = ws + (side ? OFF_T2R : OFF_T2L);
            float* Ls = sm;          // [32a][16b][8w pad->12], row stride 200
            float* ms = sm + 6400;   // [32a][2i][16p]
            float* hs = sm + 7424;   // [16wi][16xj]
            hs[t] = h[((t >> 4) >> 1) * 32 + ((t & 15) >> 1) * 4 + ((t >> 4) & 1) * 2 + (t & 1)];
            int b_l = t & 15, p_l = t >> 4;
            float acc[8][2];
#pragma unroll
            for (int w = 0; w < 8; ++w) { acc[w][0] = 0.f; acc[w][1] = 0.f; }
            for (int c = 0; c < 4; ++c) {
                int a0 = c * 32;
                __syncthreads();
#pragma unroll
                for (int u = 0; u < 4; ++u) {
                    int e = u * 256 + t;
                    int aa = e >> 5, w = (e >> 2) & 7, bq = e & 3;
                    const float4 v = *(const float4*)&Lsrc[(a0 + aa) * 1024 + w * 128 + b0 + bq * 4];
                    float* dst = &Ls[aa * 200 + bq * 48 + w];
                    dst[0] = v.x; dst[12] = v.y; dst[24] = v.z; dst[36] = v.w;
                }
                {
                    int aa = t >> 3, i = (t >> 2) & 1, pq = t & 3;
                    const float4 v = *(const float4*)&m[(a0 + aa) * 256 + i * 128 + p0 + pq * 4];
                    *(float4*)&ms[aa * 32 + i * 16 + pq * 4] = v;
                }
                __syncthreads();
#pragma unroll 4
                for (int aa = 0; aa < 32; ++aa) {
                    float4 l0 = *(float4*)&Ls[aa * 200 + b_l * 12];
                    float4 l1 = *(float4*)&Ls[aa * 200 + b_l * 12 + 4];
                    float m0 = ms[aa * 32 + p_l];
                    float m1 = ms[aa * 32 + 16 + p_l];
                    acc[0][0] += l0.x * m0; acc[0][1] += l0.x * m1;
                    acc[1][0] += l0.y * m0; acc[1][1] += l0.y * m1;
                    acc[2][0] += l0.z * m0; acc[2][1] += l0.z * m1;
                    acc[3][0] += l0.w * m0; acc[3][1] += l0.w * m1;
                    acc[4][0] += l1.x * m0; acc[4][1] += l1.x * m1;
                    acc[5][0] += l1.y * m0; acc[5][1] += l1.y * m1;
                    acc[6][0] += l1.z * m0; acc[6][1] += l1.z * m1;
                    acc[7][0] += l1.w * m0; acc[7][1] += l1.w * m1;
                }
            }
            float o[16];
#pragma unroll
            for (int xj = 0; xj < 16; ++xj) o[xj] = 0.f;
#pragma unroll
            for (int wi = 0; wi < 16; ++wi) {
                float tv = acc[wi >> 1][wi & 1];
                float4 h0 = *(float4*)&hs[wi * 16];
                float4 h1 = *(float4*)&hs[wi * 16 + 4];
                float4 h2 = *(float4*)&hs[wi * 16 + 8];
                float4 h3 = *(float4*)&hs[wi * 16 + 12];
                o[0] += tv * h0.x;  o[1] += tv * h0.y;  o[2] += tv * h0.z;  o[3] += tv * h0.w;
                o[4] += tv * h1.x;  o[5] += tv * h1.y;  o[6] += tv * h1.z;  o[7] += tv * h1.w;
                o[8] += tv * h2.x;  o[9] += tv * h2.y;  o[10] += tv * h2.z; o[11] += tv * h2.w;
                o[12] += tv * h3.x; o[13] += tv * h3.y; o[14] += tv * h3.z; o[15] += tv * h3.w;
            }
            int b = b0 + b_l, p = p0 + p_l;
            int base = p * 2048 + b * 2; // T2[p][x][b][j]
#pragma unroll
            for (int x = 0; x < 8; ++x) {
                float2 v; v.x = o[x * 2]; v.y = o[x * 2 + 1];
                *(float2*)&T2[base + x * 256] = v;
            }
        } else if (bid < 192) {
            int nb = bid - 128;
            int side = nb >> 5;
            int nn = nb & 31;
            int b0 = (nn & 3) * 32;
            int c0 = (nn >> 2) * 32;
            const float* Nsrc = ws + (side ? OFF_NR : OFF_NL);
            const float* m = side ? (ws + OFF_MREV + k * MSZ) : (Min + k * MSZ);
            float* Tn = ws + (side ? OFF_TNR : OFF_TNL);
            float* As = sm;         // [32][33]
            float* Bs = sm + 1056;  // [32][33]
            int ty = t >> 4, tx = t & 15;
            float a00 = 0, a01 = 0, a10 = 0, a11 = 0;
            for (int c = 0; c < 4; ++c) {
                int a0 = c * 32;
                __syncthreads();
                for (int u = 0; u < 4; ++u) {
                    int e = u * 256 + t;
                    int kk = e >> 5, col = e & 31;
                    As[kk * 33 + col] = Nsrc[(a0 + kk) * 128 + b0 + col];
                    Bs[kk * 33 + col] = m[(a0 + kk) * 256 + c0 + col];
                }
                __syncthreads();
                for (int kk = 0; kk < 32; ++kk) {
                    float av0 = As[kk * 33 + 2 * ty], av1 = As[kk * 33 + 2 * ty + 1];
                    float bv0 = Bs[kk * 33 + 2 * tx], bv1 = Bs[kk * 33 + 2 * tx + 1];
                    a00 += av0 * bv0;
                    a01 += av0 * bv1;
                    a10 += av1 * bv0;
                    a11 += av1 * bv1;
                }
            }
            int b_ = b0 + 2 * ty;
            int ip0 = c0 + 2 * tx, ip1 = ip0 + 1;
            int p0_ = ip0 & 127, i0 = ip0 >> 7;
            int p1_ = ip1 & 127, i1 = ip1 >> 7;
            Tn[p0_ * 256 + b_ * 2 + i0] = a00;
            Tn[p1_ * 256 + b_ * 2 + i1] = a01;
            Tn[p0_ * 256 + (b_ + 1) * 2 + i0] = a10;
            Tn[p1_ * 256 + (b_ + 1) * 2 + i1] = a11;
        }
        gbar(bar, ++ep);

        // ================= phase B (was k_B, 144 tasks) =================
        if (bid < 144) {
            float* As = sm;              // [32][34]
            float* Bs = sm + 32 * 34;    // [32][68]
            const float* A;
            const float* B;
            float* C;
            int r0, c0;
            if (bid < 128) {
                int side = bid >> 6;
                int eb = bid & 63;
                r0 = (eb & 31) * 32;
                c0 = (eb >> 5) * 64;
                A = ws + (side ? OFF_T2R : OFF_T2L);
                B = side ? (ws + OFF_MREV + k * MSZ) : (Min + k * MSZ);
                C = ws + (side ? OFF_LR : OFF_LL);
            } else {
                int nb = bid - 128;
                int side = nb >> 3;
                int nn = nb & 7;
                r0 = (nn & 3) * 32;
                c0 = (nn >> 2) * 64;
                A = ws + (side ? OFF_TNR : OFF_TNL);
                B = side ? (ws + OFF_MREV + k * MSZ) : (Min + k * MSZ);
                C = ws + (side ? OFF_NR : OFF_NL);
            }
            int ty = t >> 4, tx = t & 15;
            float a00 = 0, a01 = 0, a02 = 0, a03 = 0;
            float a10 = 0, a11 = 0, a12 = 0, a13 = 0;
            for (int c = 0; c < 8; ++c) {
                int k0 = c * 32;
                __syncthreads();
                {
                    int rr = t >> 3, kq = t & 7;
                    const float4 v = *(const float4*)&A[(r0 + rr) * 256 + k0 + kq * 4];
                    float* dst = &As[kq * 136 + rr];
                    dst[0] = v.x; dst[34] = v.y; dst[68] = v.z; dst[102] = v.w;
                }
#pragma unroll
                for (int u = 0; u < 2; ++u) {
                    int e = u * 256 + t;
                    int kk = e >> 4, cq = e & 15;
                    const float4 v = *(const float4*)&B[(k0 + kk) * 128 + c0 + cq * 4];
                    *(float4*)&Bs[kk * 68 + cq * 4] = v;
                }
                __syncthreads();
#pragma unroll 8
                for (int kk = 0; kk < 32; ++kk) {
                    float2 av = *(float2*)&As[kk * 34 + 2 * ty];
                    float4 bv = *(float4*)&Bs[kk * 68 + 4 * tx];
                    a00 += av.x * bv.x; a01 += av.x * bv.y; a02 += av.x * bv.z; a03 += av.x * bv.w;
                    a10 += av.y * bv.x; a11 += av.y * bv.y; a12 += av.y * bv.z; a13 += av.y * bv.w;
                }
            }
            int r = r0 + 2 * ty, cc = c0 + 4 * tx;
            float4 v0; v0.x = a00; v0.y = a01; v0.z = a02; v0.w = a03;
            float4 v1; v1.x = a10; v1.y = a11; v1.z = a12; v1.w = a13;
            *(float4*)&C[r * 128 + cc] = v0;
            *(float4*)&C[(r + 1) * 128 + cc] = v1;
        }
        gbar(bar, ++ep);
    }

    // ================= dot partials (was k_dot, 128 tasks) =================
    if (bid < 128) {
        float* se = sm;
        float* sn = sm + 256;
        const float* LL = ws + OFF_LL;
        const float* LR = ws + OFF_LR;
        float e = 0.f;
#pragma unroll
        for (int u = 0; u < 4; ++u) {
            int i = bid * 1024 + u * 256 + t;
            e += LL[i] * LR[i];
        }
        float n = 0.f;
        if (t < 128) {
            int i = bid * 128 + t;
            n = ws[OFF_NL + i] * ws[OFF_NR + i];
        }
        se[t] = e;
        sn[t] = n;
        __syncthreads();
        for (int s = 128; s > 0; s >>= 1) {
            if (t < s) { se[t] += se[t + s]; sn[t] += sn[t + s]; }
            __syncthreads();
        }
        if (t == 0) {
            ws[OFF_PART + bid] = se[0];
            ws[OFF_PARTN + bid] = sn[0];
        }
    }
    gbar(bar, ++ep);

    // ================= final reduce + loss (was k_loss) =================
    if (bid == 0) {
        float* se = sm;
        float* sn = sm + 128;
        if (t < 128) {
            se[t] = ws[OFF_PART + t];
            sn[t] = ws[OFF_PARTN + t];
        }
        __syncthreads();
        for (int s = 64; s > 0; s >>= 1) {
            if (t < s) { se[t] += se[t + s]; sn[t] += sn[t + s]; }
            __syncthreads();
        }
        if (t == 0) {
            float E = se[0], Nm = sn[0];
            out[0] = E;
            out[1] = Nm;
            out[2] = E / Nm;
            out[3] = fmaxf(Nm - 10000.0f, 0.0f);
        }
    }
}

extern "C" void kernel_launch(void* const* d_in, const int* in_sizes, int n_in,
                              void* d_out, int out_size, void* d_ws, size_t ws_size,
                              hipStream_t stream) {
    const float* Min = (const float*)d_in[0];
    const float* Hin = (const float*)d_in[1];
    float* ws = (float*)d_ws;
    float* out = (float*)d_out;
    (void)in_sizes; (void)n_in; (void)out_size; (void)ws_size;

    k_bzero<<<dim3((BAR_INTS + 255) / 256), dim3(256), 0, stream>>>(ws);
    k_sweep<<<dim3(NBLK), dim3(256), 0, stream>>>(Min, Hin, ws, out);
}

// Round 5
// 642.267 us; speedup vs baseline: 1.9930x; 1.4417x over previous
//
#include <hip/hip_runtime.h>

// VariationalMPS: <M|H|M> / <M|M> via split-half environment sweeps.
// R7: persistent kernel, write-once per-step buffers, PLAIN cached stores.
// Coherence: every 128B line has exactly ONE writer block that writes the
// WHOLE line (Tn relaid [p][i][b]; PART stride-32), so no consumer L2 can hold
// a stale/partial copy (write-once => no pre-write residency; same-XCD
// consumers hit the writer's fully-valid resident line). Publication to LLC:
// ONE buffer_wbl2 per XCD per barrier by an elected leader (XCC_ID + CAS).
// No buffer_inv at all => constants stay L2-resident across all 20 steps.
// R6's failure: Tn[p][b][i] and PART had multi-writer lines; the writer-XCD's
// partially-valid line was read by same-XCD consumers (norm-only 1e-2 error).

#define D 128
#define W 8
#define NS 40
#define HALF 20
#define MSZ (D * 2 * D)      // 32768
#define HSZ (W * W * 2 * 2)  // 256
#define LSZ (D * W * D)      // 131072
#define NSZ (D * D)          // 16384
#define T2SZ (D * W * D * 2) // 262144
#define TNSZ (D * 2 * D)     // 32768

// Per-step unique buffers (write-once dataflow).
#define OFF_L 0
#define L_BUF(side, k) (OFF_L + ((side) * (HALF + 1) + (k)) * LSZ)      // k=0..20
#define OFF_N (OFF_L + 2 * (HALF + 1) * LSZ)
#define N_BUF(side, k) (OFF_N + ((side) * (HALF + 1) + (k)) * NSZ)      // k=0..20
#define OFF_T2 (OFF_N + 2 * (HALF + 1) * NSZ)
#define T2_BUF(side, k) (OFF_T2 + ((side) * HALF + (k)) * T2SZ)        // k=0..19
#define OFF_TN (OFF_T2 + 2 * HALF * T2SZ)
#define TN_BUF(side, k) (OFF_TN + ((side) * HALF + (k)) * TNSZ)        // k=0..19
#define OFF_MREV (OFF_TN + 2 * HALF * TNSZ)
#define OFF_HREV (OFF_MREV + HALF * MSZ)
#define OFF_PART (OFF_HREV + HALF * HSZ)    // 128 energy partials, stride 32
#define OFF_PARTN (OFF_PART + 128 * 32)     // 128 norm partials, stride 32
#define WS_FLOATS (OFF_PARTN + 128 * 32)

#define NBLK 192                 // <= 256 CUs -> co-resident by construction
#define OFF_BAR WS_FLOATS        // barrier state (ints), zeroed by k_bzero
// bar layout (32-int = 128B spaced): arrive[b]=bar[32*b]; clean[x]=bar[32*(NBLK+x)];
// claim[x]=bar[32*(NBLK+8+x)]
#define BAR_INTS (32 * (NBLK + 16))

#define INIT_TOT (2 * LSZ + 2 * NSZ)

__device__ __forceinline__ int ld_rlx(int* p) {
    return __hip_atomic_load(p, __ATOMIC_RELAXED, __HIP_MEMORY_SCOPE_AGENT);
}
__device__ __forceinline__ void st_rlx(int* p, int v) {
    __hip_atomic_store(p, v, __ATOMIC_RELAXED, __HIP_MEMORY_SCOPE_AGENT);
}

__global__ __launch_bounds__(256) void k_bzero(float* ws) {
    int idx = blockIdx.x * 256 + threadIdx.x;
    int* bar = (int*)(ws + OFF_BAR);
    if (idx < BAR_INTS) bar[idx] = 0;
}

// Grid barrier: all blocks drain vmcnt + syncthreads, arrive; ALL blocks gather
// all arrivals (lanes t<NBLK poll distinct slots); per-XCD leader then does ONE
// release fence (waitcnt + buffer_wbl2, publishing the whole XCD's dirty lines
// to the LLC) and stores clean[xcd]; everyone polls clean[] of claimed XCDs.
__device__ __forceinline__ void gbar(int* bar, int epoch, int myxcd, int isLead,
                                     int* claimLds) {
    int t = threadIdx.x;
    asm volatile("s_waitcnt vmcnt(0)" ::: "memory");
    __syncthreads();
    if (t == 0) st_rlx(&bar[32 * blockIdx.x], epoch);
    if (t < NBLK) {
        while (ld_rlx(&bar[32 * t]) < epoch) __builtin_amdgcn_s_sleep(1);
    }
    __syncthreads();
    if (epoch == 1) {
        // all arrivals seen => all claim CASes are globally visible; snapshot.
        if (t < 8) claimLds[t] = ld_rlx(&bar[32 * (NBLK + 8 + t)]);
        __syncthreads();
    }
    if (isLead && t == 0) {
        __builtin_amdgcn_fence(__ATOMIC_RELEASE, "agent");  // waitcnt + buffer_wbl2
        st_rlx(&bar[32 * (NBLK + myxcd)], epoch);
    }
    if (t < 8 && claimLds[t]) {
        while (ld_rlx(&bar[32 * (NBLK + t)]) < epoch) __builtin_amdgcn_s_sleep(1);
    }
    __syncthreads();
}

__global__ __launch_bounds__(256) void k_sweep(const float* __restrict__ Min,
                                               const float* __restrict__ Hin,
                                               float* __restrict__ ws,
                                               float* __restrict__ out) {
    __shared__ float sm[7680];
    __shared__ int claimLds[8];
    __shared__ int leadLds;
    int* bar = (int*)(ws + OFF_BAR);
    const int bid = blockIdx.x;
    const int t = threadIdx.x;
    int ep = 0;

    // ---- leader election: one leader per (claimed) XCD ----
    int myxcd;
    asm volatile("s_getreg_b32 %0, hwreg(HW_REG_XCC_ID)" : "=s"(myxcd));
    myxcd &= 7;
    if (t == 0) {
        int old = atomicCAS(&bar[32 * (NBLK + 8 + myxcd)], 0, bid + 1);
        leadLds = (old == 0);
    }
    __syncthreads();
    const int isLead = leadLds;

    // ---- phase -1a: env init (one-hot L0/N0 for both sides) ----
    for (int idx = bid * 256 + t; idx < INIT_TOT; idx += NBLK * 256) {
        int off;
        float v = 0.f;
        if (idx < LSZ) {
            off = L_BUF(0, 0) + idx;
            if (idx == 0) v = 1.f;                 // L_left[0,0,0]
        } else if (idx < 2 * LSZ) {
            int r = idx - LSZ;
            off = L_BUF(1, 0) + r;
            if (r == (W - 1) * D) v = 1.f;         // L_right[0,W-1,0]
        } else if (idx < 2 * LSZ + NSZ) {
            int r = idx - 2 * LSZ;
            off = N_BUF(0, 0) + r;
            if (r == 0) v = 1.f;                   // N_left[0,0]
        } else {
            int r = idx - 2 * LSZ - NSZ;
            off = N_BUF(1, 0) + r;
            if (r == 0) v = 1.f;                   // N_right[0,0]
        }
        ws[off] = v;
    }
    // ---- phase -1b: Mrev/Hrev prep ----
    for (int idx = bid * 256 + t; idx < HALF * MSZ + HALF * HSZ; idx += NBLK * 256) {
        if (idx < HALF * MSZ) {
            int kk = idx >> 15;
            int r = idx & (MSZ - 1);
            int p = r >> 8;
            int i = (r >> 7) & 1;
            int a = r & 127;
            ws[OFF_MREV + idx] = Min[(NS - 1 - kk) * MSZ + a * 256 + i * 128 + p];
        } else {
            int idx2 = idx - HALF * MSZ;
            int kk = idx2 >> 8;
            int r = idx2 & 255;
            int x = r >> 5, w = (r >> 2) & 7, i = (r >> 1) & 1, j = r & 1;
            ws[OFF_HREV + idx2] = Hin[(NS - 1 - kk) * HSZ + w * 32 + x * 4 + i * 2 + j];
        }
    }
    gbar(bar, ++ep, myxcd, isLead, claimLds);

    for (int k = 0; k < HALF; ++k) {
        // ================= phase A (192 tasks) =================
        if (bid < 128) {
            int side = bid >> 6;
            int eb = bid & 63;
            int b0 = (eb & 7) * 16;
            int p0 = (eb >> 3) * 16;
            const float* Lsrc = ws + L_BUF(side, k);
            const float* m = side ? (ws + OFF_MREV + k * MSZ) : (Min + k * MSZ);
            const float* h = side ? (ws + OFF_HREV + k * HSZ) : (Hin + k * HSZ);
            float* T2 = ws + T2_BUF(side, k);
            float* Ls = sm;          // [32a][16b][8w pad->12], row stride 200
            float* ms = sm + 6400;   // [32a][2i][16p]
            float* hs = sm + 7424;   // [16wi][16xj]
            hs[t] = h[((t >> 4) >> 1) * 32 + ((t & 15) >> 1) * 4 + ((t >> 4) & 1) * 2 + (t & 1)];
            int b_l = t & 15, p_l = t >> 4;
            float acc[8][2];
#pragma unroll
            for (int w = 0; w < 8; ++w) { acc[w][0] = 0.f; acc[w][1] = 0.f; }
            for (int c = 0; c < 4; ++c) {
                int a0 = c * 32;
                __syncthreads();
#pragma unroll
                for (int u = 0; u < 4; ++u) {
                    int e = u * 256 + t;
                    int aa = e >> 5, w = (e >> 2) & 7, bq = e & 3;
                    const float4 v = *(const float4*)&Lsrc[(a0 + aa) * 1024 + w * 128 + b0 + bq * 4];
                    float* dst = &Ls[aa * 200 + bq * 48 + w];
                    dst[0] = v.x; dst[12] = v.y; dst[24] = v.z; dst[36] = v.w;
                }
                {
                    int aa = t >> 3, i = (t >> 2) & 1, pq = t & 3;
                    const float4 v = *(const float4*)&m[(a0 + aa) * 256 + i * 128 + p0 + pq * 4];
                    *(float4*)&ms[aa * 32 + i * 16 + pq * 4] = v;
                }
                __syncthreads();
#pragma unroll 4
                for (int aa = 0; aa < 32; ++aa) {
                    float4 l0 = *(float4*)&Ls[aa * 200 + b_l * 12];
                    float4 l1 = *(float4*)&Ls[aa * 200 + b_l * 12 + 4];
                    float m0 = ms[aa * 32 + p_l];
                    float m1 = ms[aa * 32 + 16 + p_l];
                    acc[0][0] += l0.x * m0; acc[0][1] += l0.x * m1;
                    acc[1][0] += l0.y * m0; acc[1][1] += l0.y * m1;
                    acc[2][0] += l0.z * m0; acc[2][1] += l0.z * m1;
                    acc[3][0] += l0.w * m0; acc[3][1] += l0.w * m1;
                    acc[4][0] += l1.x * m0; acc[4][1] += l1.x * m1;
                    acc[5][0] += l1.y * m0; acc[5][1] += l1.y * m1;
                    acc[6][0] += l1.z * m0; acc[6][1] += l1.z * m1;
                    acc[7][0] += l1.w * m0; acc[7][1] += l1.w * m1;
                }
            }
            float o[16];
#pragma unroll
            for (int xj = 0; xj < 16; ++xj) o[xj] = 0.f;
#pragma unroll
            for (int wi = 0; wi < 16; ++wi) {
                float tv = acc[wi >> 1][wi & 1];
                float4 h0 = *(float4*)&hs[wi * 16];
                float4 h1 = *(float4*)&hs[wi * 16 + 4];
                float4 h2 = *(float4*)&hs[wi * 16 + 8];
                float4 h3 = *(float4*)&hs[wi * 16 + 12];
                o[0] += tv * h0.x;  o[1] += tv * h0.y;  o[2] += tv * h0.z;  o[3] += tv * h0.w;
                o[4] += tv * h1.x;  o[5] += tv * h1.y;  o[6] += tv * h1.z;  o[7] += tv * h1.w;
                o[8] += tv * h2.x;  o[9] += tv * h2.y;  o[10] += tv * h2.z; o[11] += tv * h2.w;
                o[12] += tv * h3.x; o[13] += tv * h3.y; o[14] += tv * h3.z; o[15] += tv * h3.w;
            }
            int b = b0 + b_l, p = p0 + p_l;
            int base = p * 2048 + b * 2; // T2[p][x][b][j]
#pragma unroll
            for (int x = 0; x < 8; ++x) {
                float2 v; v.x = o[x * 2]; v.y = o[x * 2 + 1];
                *(float2*)&T2[base + x * 256] = v;
            }
        } else if (bid < 192) {
            int nb = bid - 128;
            int side = nb >> 5;
            int nn = nb & 31;
            int b0 = (nn & 3) * 32;
            int c0 = (nn >> 2) * 32;
            const float* Nsrc = ws + N_BUF(side, k);
            const float* m = side ? (ws + OFF_MREV + k * MSZ) : (Min + k * MSZ);
            float* Tn = ws + TN_BUF(side, k);
            float* As = sm;         // [32][33]
            float* Bs = sm + 1056;  // [32][33]
            int ty = t >> 4, tx = t & 15;
            float a00 = 0, a01 = 0, a10 = 0, a11 = 0;
            for (int c = 0; c < 4; ++c) {
                int a0 = c * 32;
                __syncthreads();
                for (int u = 0; u < 4; ++u) {
                    int e = u * 256 + t;
                    int kk = e >> 5, col = e & 31;
                    As[kk * 33 + col] = Nsrc[(a0 + kk) * 128 + b0 + col];
                    Bs[kk * 33 + col] = m[(a0 + kk) * 256 + c0 + col];
                }
                __syncthreads();
                for (int kk = 0; kk < 32; ++kk) {
                    float av0 = As[kk * 33 + 2 * ty], av1 = As[kk * 33 + 2 * ty + 1];
                    float bv0 = Bs[kk * 33 + 2 * tx], bv1 = Bs[kk * 33 + 2 * tx + 1];
                    a00 += av0 * bv0;
                    a01 += av0 * bv1;
                    a10 += av1 * bv0;
                    a11 += av1 * bv1;
                }
            }
            // Tn layout [p][i][b] (single-writer whole lines): idx = p*256+i*128+b
            int b_ = b0 + 2 * ty;
            int ip0 = c0 + 2 * tx, ip1 = ip0 + 1;
            int p0_ = ip0 & 127, i0 = ip0 >> 7;
            int p1_ = ip1 & 127, i1 = ip1 >> 7;
            float2 va; va.x = a00; va.y = a10;   // (b_, b_+1) at (p0_, i0)
            float2 vb; vb.x = a01; vb.y = a11;   // (b_, b_+1) at (p1_, i1)
            *(float2*)&Tn[p0_ * 256 + i0 * 128 + b_] = va;
            *(float2*)&Tn[p1_ * 256 + i1 * 128 + b_] = vb;
        }
        gbar(bar, ++ep, myxcd, isLead, claimLds);

        // ================= phase B (144 tasks) =================
        if (bid < 144) {
            float* As = sm;              // [32][34]
            float* Bs = sm + 32 * 34;    // [32][68]
            const float* A;
            const float* B;
            float* C;
            int r0, c0;
            bool isNorm = (bid >= 128);
            if (bid < 128) {
                int side = bid >> 6;
                int eb = bid & 63;
                r0 = (eb & 31) * 32;
                c0 = (eb >> 5) * 64;
                A = ws + T2_BUF(side, k);
                B = side ? (ws + OFF_MREV + k * MSZ) : (Min + k * MSZ);
                C = ws + L_BUF(side, k + 1);
            } else {
                int nb = bid - 128;
                int side = nb >> 3;
                int nn = nb & 7;
                r0 = (nn & 3) * 32;
                c0 = (nn >> 2) * 64;
                A = ws + TN_BUF(side, k);
                B = side ? (ws + OFF_MREV + k * MSZ) : (Min + k * MSZ);
                C = ws + N_BUF(side, k + 1);
            }
            int ty = t >> 4, tx = t & 15;
            float a00 = 0, a01 = 0, a02 = 0, a03 = 0;
            float a10 = 0, a11 = 0, a12 = 0, a13 = 0;
            for (int c = 0; c < 8; ++c) {
                int k0 = c * 32;
                __syncthreads();
                {
                    int rr = t >> 3, kq = t & 7;
                    const float4 v = *(const float4*)&A[(r0 + rr) * 256 + k0 + kq * 4];
                    float* dst = &As[kq * 136 + rr];
                    dst[0] = v.x; dst[34] = v.y; dst[68] = v.z; dst[102] = v.w;
                }
#pragma unroll
                for (int u = 0; u < 2; ++u) {
                    int e = u * 256 + t;
                    int kk = e >> 4, cq = e & 15;
                    int row = k0 + kk;
                    // norm: A-cols are k=i*128+b (Tn [p][i][b]); B row = m[b][i][.]
                    int baddr = isNorm ? ((row & 127) * 256 + (row >> 7) * 128)
                                       : row * 128;
                    const float4 v = *(const float4*)&B[baddr + c0 + cq * 4];
                    *(float4*)&Bs[kk * 68 + cq * 4] = v;
                }
                __syncthreads();
#pragma unroll 8
                for (int kk = 0; kk < 32; ++kk) {
                    float2 av = *(float2*)&As[kk * 34 + 2 * ty];
                    float4 bv = *(float4*)&Bs[kk * 68 + 4 * tx];
                    a00 += av.x * bv.x; a01 += av.x * bv.y; a02 += av.x * bv.z; a03 += av.x * bv.w;
                    a10 += av.y * bv.x; a11 += av.y * bv.y; a12 += av.y * bv.z; a13 += av.y * bv.w;
                }
            }
            int r = r0 + 2 * ty, cc = c0 + 4 * tx;
            float4 v0; v0.x = a00; v0.y = a01; v0.z = a02; v0.w = a03;
            float4 v1; v1.x = a10; v1.y = a11; v1.z = a12; v1.w = a13;
            *(float4*)&C[r * 128 + cc] = v0;
            *(float4*)&C[(r + 1) * 128 + cc] = v1;
        }
        gbar(bar, ++ep, myxcd, isLead, claimLds);
    }

    // ================= dot partials (128 tasks) =================
    if (bid < 128) {
        float* se = sm;
        float* sn = sm + 256;
        const float* LL = ws + L_BUF(0, HALF);
        const float* LR = ws + L_BUF(1, HALF);
        float e = 0.f;
#pragma unroll
        for (int u = 0; u < 4; ++u) {
            int i = bid * 1024 + u * 256 + t;
            e += LL[i] * LR[i];
        }
        float n = 0.f;
        if (t < 128) {
            int i = bid * 128 + t;
            n = ws[N_BUF(0, HALF) + i] * ws[N_BUF(1, HALF) + i];
        }
        se[t] = e;
        sn[t] = n;
        __syncthreads();
        for (int s = 128; s > 0; s >>= 1) {
            if (t < s) { se[t] += se[t + s]; sn[t] += sn[t + s]; }
            __syncthreads();
        }
        if (t == 0) {
            ws[OFF_PART + bid * 32] = se[0];    // stride-32: one line per writer
            ws[OFF_PARTN + bid * 32] = sn[0];
        }
    }
    gbar(bar, ++ep, myxcd, isLead, claimLds);

    // ================= final reduce + loss =================
    if (bid == 0) {
        float* se = sm;
        float* sn = sm + 128;
        if (t < 128) {
            se[t] = ws[OFF_PART + t * 32];
            sn[t] = ws[OFF_PARTN + t * 32];
        }
        __syncthreads();
        for (int s = 64; s > 0; s >>= 1) {
            if (t < s) { se[t] += se[t + s]; sn[t] += sn[t + s]; }
            __syncthreads();
        }
        if (t == 0) {
            float E = se[0], Nm = sn[0];
            out[0] = E;
            out[1] = Nm;
            out[2] = E / Nm;
            out[3] = fmaxf(Nm - 10000.0f, 0.0f);
        }
    }
}

extern "C" void kernel_launch(void* const* d_in, const int* in_sizes, int n_in,
                              void* d_out, int out_size, void* d_ws, size_t ws_size,
                              hipStream_t stream) {
    const float* Min = (const float*)d_in[0];
    const float* Hin = (const float*)d_in[1];
    float* ws = (float*)d_ws;
    float* out = (float*)d_out;
    (void)in_sizes; (void)n_in; (void)out_size; (void)ws_size;

    k_bzero<<<dim3((BAR_INTS + 255) / 256), dim3(256), 0, stream>>>(ws);
    k_sweep<<<dim3(NBLK), dim3(256), 0, stream>>>(Min, Hin, ws, out);
}

// Round 7
// 476.826 us; speedup vs baseline: 2.6845x; 1.3470x over previous
//
#include <hip/hip_runtime.h>

// VariationalMPS: <M|H|M> / <M|M> via split-half environment sweeps.
// R9: back to MULTI-LAUNCH (dispatch-boundary coherence — proven correct in R2;
// persistent-kernel barriers cost more than graph-replay launch gaps: R7=642us
// with leader-wbl2, R8 fence-free = WRONG since sc1 stores stay dirty in L2).
// New: SITE PAIRING. Prep contracts adjacent sites: M2[m]=M[2m]*M[2m+1]
// (D x 4 x D, phys dim 4) and H2[m] (8x8x4x4, MPO bond contracted). The sweep
// is 10 paired steps per half instead of 20 (same total FLOPs, half the serial
// dependencies). Rev side: (A*B)^T = B^T*A^T => rev pair kr = bond-transposed
// M2[19-kr] / w<->x-swapped H2[19-kr], same transpose pattern as validated
// single-site Mrev/Hrev. Launches: 42 -> 24.

#define D 128
#define W 8
#define NS 40
#define NPAIR 20
#define HALF2 10
#define MSZ (D * 2 * D)        // 32768 (input M site)
#define HSZ (W * W * 2 * 2)    // 256   (input H site)
#define M2SZ (D * 4 * D)       // 65536 (paired M: [a][I][c], a*512+I*128+c)
#define H2SZ (W * W * 4 * 4)   // 1024  (paired H: [w][x][I][J], w*128+x*16+I*4+J)
#define LSZ (D * W * D)        // 131072 ([a][w][b] = a*1024+w*128+b)
#define NSZ (D * D)            // 16384
#define T2SZ (D * W * D * 4)   // 524288 ([p][x][b][J] = p*4096+x*512+b*4+J)
#define TNSZ (4 * D * D)       // 65536  ([I][p][b] = I*16384+p*128+b)

#define OFF_M2 0
#define OFF_MR2 (OFF_M2 + NPAIR * M2SZ)        // 10 rev pairs
#define OFF_H2 (OFF_MR2 + HALF2 * M2SZ)
#define OFF_HR2 (OFF_H2 + NPAIR * H2SZ)
#define OFF_LL (OFF_HR2 + HALF2 * H2SZ)
#define OFF_LR (OFF_LL + LSZ)
#define OFF_NL (OFF_LR + LSZ)
#define OFF_NR (OFF_NL + NSZ)
#define OFF_T2L (OFF_NR + NSZ)
#define OFF_T2R (OFF_T2L + T2SZ)
#define OFF_TNL (OFF_T2R + T2SZ)
#define OFF_TNR (OFF_TNL + TNSZ)
#define OFF_PART (OFF_TNR + TNSZ)
#define OFF_PARTN (OFF_PART + 128)

// ---------------- prep1: pair GEMMs M2 (640 blocks) + H2 (block 640) --------
// M2[m][a][I][c], I=(i1,i2): sum_b M[2m][a,i1,b] * M[2m+1][b,i2,c].
// GEMM view: rows (a,i1) 256, cols (i2,c) 256, k=b 128. Tile 32x64.
__global__ __launch_bounds__(256) void k_prep1(const float* __restrict__ Min,
                                               const float* __restrict__ Hin,
                                               float* __restrict__ ws) {
    __shared__ float As[32 * 34];
    __shared__ float Bs[32 * 68];
    int bid = blockIdx.x, t = threadIdx.x;
    if (bid < 640) {
        int m = bid >> 5, tile = bid & 31;
        int r0 = (tile & 7) * 32, c0 = (tile >> 3) * 64;
        const float* A = Min + (2 * m) * MSZ;       // [a][i1][b] = a*256+i1*128+b
        const float* B = Min + (2 * m + 1) * MSZ;   // [b][i2][c] = b*256+i2*128+c
        float* C = ws + OFF_M2 + m * M2SZ;
        int ty = t >> 4, tx = t & 15;
        float a00 = 0, a01 = 0, a02 = 0, a03 = 0;
        float a10 = 0, a11 = 0, a12 = 0, a13 = 0;
        for (int c = 0; c < 4; ++c) {
            int k0 = c * 32;
            __syncthreads();
            {   // stage A 32r x 32k, transposed into As[kk][rr] (stride 34)
                int rr = t >> 3, kq = t & 7;
                int row = r0 + rr;
                const float4 v = *(const float4*)&A[(row >> 1) * 256 + (row & 1) * 128 + k0 + kq * 4];
                float* dst = &As[kq * 136 + rr];
                dst[0] = v.x; dst[34] = v.y; dst[68] = v.z; dst[102] = v.w;
            }
#pragma unroll
            for (int u = 0; u < 2; ++u) {  // stage B 32k x 64c; cols (i2,c): col=i2*128+c
                int e = u * 256 + t;
                int kk = e >> 4, cq = e & 15;
                const float4 v = *(const float4*)&B[(k0 + kk) * 256 + c0 + cq * 4];
                *(float4*)&Bs[kk * 68 + cq * 4] = v;
            }
            __syncthreads();
#pragma unroll 8
            for (int kk = 0; kk < 32; ++kk) {
                float2 av = *(float2*)&As[kk * 34 + 2 * ty];
                float4 bv = *(float4*)&Bs[kk * 68 + 4 * tx];
                a00 += av.x * bv.x; a01 += av.x * bv.y; a02 += av.x * bv.z; a03 += av.x * bv.w;
                a10 += av.y * bv.x; a11 += av.y * bv.y; a12 += av.y * bv.z; a13 += av.y * bv.w;
            }
        }
        int r = r0 + 2 * ty, cc = c0 + 4 * tx;       // r even: (a, i1=0) and (a, i1=1)
        int a = r >> 1, i2 = cc >> 7, cd = cc & 127;
        float4 v0; v0.x = a00; v0.y = a01; v0.z = a02; v0.w = a03;
        float4 v1; v1.x = a10; v1.y = a11; v1.z = a12; v1.w = a13;
        *(float4*)&C[a * 512 + (0 * 2 + i2) * 128 + cd] = v0;   // i1=0
        *(float4*)&C[a * 512 + (1 * 2 + i2) * 128 + cd] = v1;   // i1=1
    } else {
        // H2[m][w][x][I][J] = sum_v H[2m][w,v,i1,j1] * H[2m+1][v,x,i2,j2]
        for (int idx = t; idx < NPAIR * H2SZ; idx += 256) {
            int m = idx >> 10, r = idx & 1023;
            int w = r >> 7, x = (r >> 4) & 7, I = (r >> 2) & 3, J = r & 3;
            int i1 = I >> 1, i2 = I & 1, j1 = J >> 1, j2 = J & 1;
            const float* Ha = Hin + (2 * m) * HSZ;
            const float* Hb = Hin + (2 * m + 1) * HSZ;
            float s = 0.f;
#pragma unroll
            for (int v = 0; v < 8; ++v)
                s += Ha[w * 32 + v * 4 + i1 * 2 + j1] * Hb[v * 32 + x * 4 + i2 * 2 + j2];
            ws[OFF_H2 + idx] = s;
        }
    }
}

// ---------------- prep2: rev transposes + env init --------------------------
#define PR_MR (HALF2 * M2SZ)                 // 655360
#define PR_HR (PR_MR + HALF2 * H2SZ)         // +10240
#define PR_TOT (PR_HR + 2 * LSZ + 2 * NSZ)   // +294912
__global__ __launch_bounds__(256) void k_prep2(float* __restrict__ ws) {
    for (int idx = blockIdx.x * 256 + threadIdx.x; idx < PR_TOT; idx += gridDim.x * 256) {
        if (idx < PR_MR) {
            // Mrev2[kr][A][I][P] = M2[19-kr][P][I][A]   (bond transpose, phys kept)
            int kr = idx >> 16, r = idx & 65535;
            int a = r >> 9, I = (r >> 7) & 3, p = r & 127;
            ws[OFF_MR2 + idx] = ws[OFF_M2 + (19 - kr) * M2SZ + p * 512 + I * 128 + a];
        } else if (idx < PR_HR) {
            // Hrev2[kr][w'][x'][IJ] = H2[19-kr][x'][w'][IJ]  (MPO bonds swapped)
            int e = idx - PR_MR;
            int kr = e >> 10, r = e & 1023;
            int w = r >> 7, x = (r >> 4) & 7, lo = r & 15;
            ws[OFF_HR2 + e] = ws[OFF_H2 + (19 - kr) * H2SZ + x * 128 + w * 16 + lo];
        } else {
            int e = idx - PR_HR;
            int off; float v = 0.f;
            if (e < LSZ)            { off = OFF_LL + e; if (e == 0) v = 1.f; }
            else if (e < 2 * LSZ)   { int r = e - LSZ; off = OFF_LR + r; if (r == (W - 1) * D) v = 1.f; }
            else if (e < 2 * LSZ + NSZ) { int r = e - 2 * LSZ; off = OFF_NL + r; if (r == 0) v = 1.f; }
            else                    { int r = e - 2 * LSZ - NSZ; off = OFF_NR + r; if (r == 0) v = 1.f; }
            ws[off] = v;
        }
    }
}

// ---------------- paired phase A -------------------------------------------
// Energy blocks 0..127 (64/side): T1[w,b,I,p] = sum_a L[a,w,b]*M2[a,I,p] on a
// 16b x 16p tile with all (w,I) per thread; h2 contraction fused in registers;
// writes T2[p][x][b][J]. Norm blocks 128..191 (32/side): Tn(b,(I,p)) =
// sum_a N[a,b]*M2[a,(I,p)], 32b x 64c tile, stored as Tn[I][p][b].
__global__ __launch_bounds__(256) void k_A2(const float* __restrict__ ws_c,
                                            float* __restrict__ ws, int k) {
    __shared__ float sm[9472];
    (void)ws_c;
    int bid = blockIdx.x, t = threadIdx.x;
    if (bid < 128) {
        int side = bid >> 6;
        int eb = bid & 63;
        int b0 = (eb & 7) * 16;
        int p0 = (eb >> 3) * 16;
        const float* Lsrc = ws + (side ? OFF_LR : OFF_LL);
        const float* m2 = ws + (side ? OFF_MR2 : OFF_M2) + k * M2SZ;
        const float* h2 = ws + (side ? OFF_HR2 : OFF_H2) + k * H2SZ;
        float* T2 = ws + (side ? OFF_T2R : OFF_T2L);
        float* Ls = sm;          // [32a][16b][8w pad->12], row stride 200 (6400)
        float* ms = sm + 6400;   // [32a][4I][16p] (2048)
        float* hs = sm + 8448;   // [32 wI][32 xJ] (1024)
#pragma unroll
        for (int u = 0; u < 4; ++u) {   // stage h2
            int e = u * 256 + t;
            int w = e >> 7, I = (e >> 5) & 3, x = (e >> 2) & 7, J = e & 3;
            hs[e] = h2[w * 128 + x * 16 + I * 4 + J];
        }
        int b_l = t & 15, p_l = t >> 4;
        float acc[8][4];
#pragma unroll
        for (int w = 0; w < 8; ++w)
#pragma unroll
            for (int I = 0; I < 4; ++I) acc[w][I] = 0.f;
        for (int c = 0; c < 4; ++c) {
            int a0 = c * 32;
            __syncthreads();
#pragma unroll
            for (int u = 0; u < 4; ++u) {   // stage L: 32a x 8w x 16b
                int e = u * 256 + t;
                int aa = e >> 5, w = (e >> 2) & 7, bq = e & 3;
                const float4 v = *(const float4*)&Lsrc[(a0 + aa) * 1024 + w * 128 + b0 + bq * 4];
                float* dst = &Ls[aa * 200 + bq * 48 + w];
                dst[0] = v.x; dst[12] = v.y; dst[24] = v.z; dst[36] = v.w;
            }
#pragma unroll
            for (int u = 0; u < 2; ++u) {   // stage M2: 32a x 4I x 16p
                int s = u * 256 + t;
                int aa = s >> 4, I = (s >> 2) & 3, pq = s & 3;
                const float4 v = *(const float4*)&m2[(a0 + aa) * 512 + I * 128 + p0 + pq * 4];
                *(float4*)&ms[aa * 64 + I * 16 + pq * 4] = v;
            }
            __syncthreads();
#pragma unroll 4
            for (int aa = 0; aa < 32; ++aa) {
                float4 l0 = *(float4*)&Ls[aa * 200 + b_l * 12];
                float4 l1 = *(float4*)&Ls[aa * 200 + b_l * 12 + 4];
                float lw[8] = {l0.x, l0.y, l0.z, l0.w, l1.x, l1.y, l1.z, l1.w};
                float mv[4];
#pragma unroll
                for (int I = 0; I < 4; ++I) mv[I] = ms[aa * 64 + I * 16 + p_l];
#pragma unroll
                for (int w = 0; w < 8; ++w)
#pragma unroll
                    for (int I = 0; I < 4; ++I) acc[w][I] += lw[w] * mv[I];
            }
        }
        // fuse h2: o[x*4+J] = sum_{w,I} acc[w][I] * hs[(w*4+I)*32 + x*4+J]
        float o[32];
#pragma unroll
        for (int xJ = 0; xJ < 32; ++xJ) o[xJ] = 0.f;
#pragma unroll
        for (int wI = 0; wI < 32; ++wI) {
            float tv = acc[wI >> 2][wI & 3];
#pragma unroll
            for (int xJ = 0; xJ < 32; ++xJ) o[xJ] += tv * hs[wI * 32 + xJ];
        }
        int b = b0 + b_l, p = p0 + p_l;
#pragma unroll
        for (int x = 0; x < 8; ++x) {
            float4 v; v.x = o[x * 4]; v.y = o[x * 4 + 1]; v.z = o[x * 4 + 2]; v.w = o[x * 4 + 3];
            *(float4*)&T2[p * 4096 + x * 512 + b * 4] = v;
        }
    } else {
        int nb = bid - 128;
        int side = nb >> 5;
        int nn = nb & 31;
        int b0 = (nn & 3) * 32;
        int c0 = (nn >> 2) * 64;     // c = (I,p) in [0,512)
        const float* Nsrc = ws + (side ? OFF_NR : OFF_NL);
        const float* m2 = ws + (side ? OFF_MR2 : OFF_M2) + k * M2SZ;
        float* Tn = ws + (side ? OFF_TNR : OFF_TNL);
        float* As = sm;          // [32][33]
        float* Bs = sm + 1056;   // [32][68]
        int ty = t >> 4, tx = t & 15;
        float a00 = 0, a01 = 0, a02 = 0, a03 = 0;
        float a10 = 0, a11 = 0, a12 = 0, a13 = 0;
        for (int c = 0; c < 4; ++c) {
            int a0 = c * 32;
            __syncthreads();
#pragma unroll
            for (int u = 0; u < 4; ++u) {
                int e = u * 256 + t;
                int kk = e >> 5, col = e & 31;
                As[kk * 33 + col] = Nsrc[(a0 + kk) * 128 + b0 + col];
            }
#pragma unroll
            for (int u = 0; u < 8; ++u) {
                int e = u * 256 + t;
                int kk = e >> 6, col = e & 63;
                Bs[kk * 68 + col] = m2[(a0 + kk) * 512 + c0 + col];
            }
            __syncthreads();
#pragma unroll 8
            for (int kk = 0; kk < 32; ++kk) {
                float2 av = *(float2*)&As[kk * 33 + 2 * ty];
                float4 bv = *(float4*)&Bs[kk * 68 + 4 * tx];
                a00 += av.x * bv.x; a01 += av.x * bv.y; a02 += av.x * bv.z; a03 += av.x * bv.w;
                a10 += av.y * bv.x; a11 += av.y * bv.y; a12 += av.y * bv.z; a13 += av.y * bv.w;
            }
        }
        int b_ = b0 + 2 * ty;
        float rowv[2][4] = {{a00, a01, a02, a03}, {a10, a11, a12, a13}};
#pragma unroll
        for (int jj = 0; jj < 4; ++jj) {
            int col = c0 + 4 * tx + jj;
            int I = col >> 7, p = col & 127;
            Tn[I * 16384 + p * 128 + b_] = rowv[0][jj];
            Tn[I * 16384 + p * 128 + b_ + 1] = rowv[1][jj];
        }
    }
}

// ---------------- paired phase B -------------------------------------------
// Energy blocks 0..127 (64/side): L'[(p,x)][q] = sum_{k=(b,J)} T2[row][k]*M2[b,J,q],
// 32x64 tile, k=512. Norm blocks 128..143 (8/side): N'[p][q] =
// sum_{k=(I,b)} Tn[I][p][b]*M2[b,I,q], 32x64 tile, k=512.
__global__ __launch_bounds__(256) void k_B2(float* __restrict__ ws, int k) {
    __shared__ float As[32 * 34];
    __shared__ float Bs[32 * 68];
    int bid = blockIdx.x, t = threadIdx.x;
    int ty = t >> 4, tx = t & 15;
    float a00 = 0, a01 = 0, a02 = 0, a03 = 0;
    float a10 = 0, a11 = 0, a12 = 0, a13 = 0;
    if (bid < 128) {
        int side = bid >> 6;
        int eb = bid & 63;
        int r0 = (eb & 31) * 32;     // rows (p,x) of 1024
        int c0 = (eb >> 5) * 64;     // q
        const float* A = ws + (side ? OFF_T2R : OFF_T2L);
        const float* B = ws + (side ? OFF_MR2 : OFF_M2) + k * M2SZ;
        float* C = ws + (side ? OFF_LR : OFF_LL);
        for (int c = 0; c < 16; ++c) {
            int k0 = c * 32;
            __syncthreads();
            {   // A[row][k], k=b*4+J contiguous
                int rr = t >> 3, kq = t & 7;
                const float4 v = *(const float4*)&A[(r0 + rr) * 512 + k0 + kq * 4];
                float* dst = &As[kq * 136 + rr];
                dst[0] = v.x; dst[34] = v.y; dst[68] = v.z; dst[102] = v.w;
            }
#pragma unroll
            for (int u = 0; u < 2; ++u) {   // B row k=(b,J): M2[b*512 + J*128 + q]
                int e = u * 256 + t;
                int kk = e >> 4, cq = e & 15;
                int row = k0 + kk;
                const float4 v = *(const float4*)&B[(row >> 2) * 512 + (row & 3) * 128 + c0 + cq * 4];
                *(float4*)&Bs[kk * 68 + cq * 4] = v;
            }
            __syncthreads();
#pragma unroll 8
            for (int kk = 0; kk < 32; ++kk) {
                float2 av = *(float2*)&As[kk * 34 + 2 * ty];
                float4 bv = *(float4*)&Bs[kk * 68 + 4 * tx];
                a00 += av.x * bv.x; a01 += av.x * bv.y; a02 += av.x * bv.z; a03 += av.x * bv.w;
                a10 += av.y * bv.x; a11 += av.y * bv.y; a12 += av.y * bv.z; a13 += av.y * bv.w;
            }
        }
        int r = r0 + 2 * ty, cc = c0 + 4 * tx;   // r even => same p for r,r+1
        float4 v0; v0.x = a00; v0.y = a01; v0.z = a02; v0.w = a03;
        float4 v1; v1.x = a10; v1.y = a11; v1.z = a12; v1.w = a13;
        *(float4*)&C[(r >> 3) * 1024 + (r & 7) * 128 + cc] = v0;
        *(float4*)&C[((r + 1) >> 3) * 1024 + ((r + 1) & 7) * 128 + cc] = v1;
    } else if (bid < 144) {
        int nb = bid - 128;
        int side = nb >> 3;
        int nn = nb & 7;
        int r0 = (nn & 3) * 32;      // p rows of 128
        int c0 = (nn >> 2) * 64;     // q
        const float* A = ws + (side ? OFF_TNR : OFF_TNL);    // [I][p][b]
        const float* B = ws + (side ? OFF_MR2 : OFF_M2) + k * M2SZ;
        float* C = ws + (side ? OFF_NR : OFF_NL);
        for (int c = 0; c < 16; ++c) {
            int k0 = c * 32;                   // k=(I,b): I=k>>7 constant per chunk
            int Ic = k0 >> 7, bc = k0 & 127;
            __syncthreads();
            {
                int rr = t >> 3, kq = t & 7;
                const float4 v = *(const float4*)&A[Ic * 16384 + (r0 + rr) * 128 + bc + kq * 4];
                float* dst = &As[kq * 136 + rr];
                dst[0] = v.x; dst[34] = v.y; dst[68] = v.z; dst[102] = v.w;
            }
#pragma unroll
            for (int u = 0; u < 2; ++u) {      // B row k=(I,b): M2[b*512 + I*128 + q]
                int e = u * 256 + t;
                int kk = e >> 4, cq = e & 15;
                const float4 v = *(const float4*)&B[(bc + kk) * 512 + Ic * 128 + c0 + cq * 4];
                *(float4*)&Bs[kk * 68 + cq * 4] = v;
            }
            __syncthreads();
#pragma unroll 8
            for (int kk = 0; kk < 32; ++kk) {
                float2 av = *(float2*)&As[kk * 34 + 2 * ty];
                float4 bv = *(float4*)&Bs[kk * 68 + 4 * tx];
                a00 += av.x * bv.x; a01 += av.x * bv.y; a02 += av.x * bv.z; a03 += av.x * bv.w;
                a10 += av.y * bv.x; a11 += av.y * bv.y; a12 += av.y * bv.z; a13 += av.y * bv.w;
            }
        }
        int r = r0 + 2 * ty, cc = c0 + 4 * tx;
        float4 v0; v0.x = a00; v0.y = a01; v0.z = a02; v0.w = a03;
        float4 v1; v1.x = a10; v1.y = a11; v1.z = a12; v1.w = a13;
        *(float4*)&C[r * 128 + cc] = v0;
        *(float4*)&C[(r + 1) * 128 + cc] = v1;
    }
}

// ---------------- dot partials + loss (unchanged from R2) -------------------
__global__ __launch_bounds__(256) void k_dot(float* __restrict__ ws) {
    __shared__ float se[256], sn[256];
    int bid = blockIdx.x, t = threadIdx.x;
    const float* LL = ws + OFF_LL;
    const float* LR = ws + OFF_LR;
    float e = 0.f;
#pragma unroll
    for (int u = 0; u < 4; ++u) {
        int i = bid * 1024 + u * 256 + t;
        e += LL[i] * LR[i];
    }
    float n = 0.f;
    if (t < 128) {
        int i = bid * 128 + t;
        n = ws[OFF_NL + i] * ws[OFF_NR + i];
    }
    se[t] = e;
    sn[t] = n;
    __syncthreads();
    for (int s = 128; s > 0; s >>= 1) {
        if (t < s) { se[t] += se[t + s]; sn[t] += sn[t + s]; }
        __syncthreads();
    }
    if (t == 0) {
        ws[OFF_PART + bid] = se[0];
        ws[OFF_PARTN + bid] = sn[0];
    }
}

__global__ __launch_bounds__(256) void k_loss(const float* __restrict__ ws,
                                              float* __restrict__ out) {
    __shared__ float se[128], sn[128];
    int t = threadIdx.x;
    if (t < 128) {
        se[t] = ws[OFF_PART + t];
        sn[t] = ws[OFF_PARTN + t];
    }
    __syncthreads();
    for (int s = 64; s > 0; s >>= 1) {
        if (t < s) { se[t] += se[t + s]; sn[t] += sn[t + s]; }
        __syncthreads();
    }
    if (t == 0) {
        float E = se[0], Nm = sn[0];
        out[0] = E;
        out[1] = Nm;
        out[2] = E / Nm;
        out[3] = fmaxf(Nm - 10000.0f, 0.0f);
    }
}

extern "C" void kernel_launch(void* const* d_in, const int* in_sizes, int n_in,
                              void* d_out, int out_size, void* d_ws, size_t ws_size,
                              hipStream_t stream) {
    const float* Min = (const float*)d_in[0];
    const float* Hin = (const float*)d_in[1];
    float* ws = (float*)d_ws;
    float* out = (float*)d_out;
    (void)in_sizes; (void)n_in; (void)out_size; (void)ws_size;

    k_prep1<<<dim3(641), dim3(256), 0, stream>>>(Min, Hin, ws);
    k_prep2<<<dim3(640), dim3(256), 0, stream>>>(ws);
    for (int k = 0; k < HALF2; ++k) {
        k_A2<<<dim3(192), dim3(256), 0, stream>>>(ws, ws, k);
        k_B2<<<dim3(144), dim3(256), 0, stream>>>(ws, k);
    }
    k_dot<<<dim3(128), dim3(256), 0, stream>>>(ws);
    k_loss<<<dim3(1), dim3(256), 0, stream>>>(ws, out);
}